// Round 5
// baseline (343.501 us; speedup 1.0000x reference)
//
#include <hip/hip_runtime.h>
#include <cmath>

// ---------------- problem constants ----------------
#define NLAYERS 100      // hidden layers (scan)
#define DIN     64       // input features
#define WDIM    100      // hidden width
#define NTT     4        // 4 n-tiles of 32 (128 neuron cols; bias col = 100)
#define RT      2        // two 32-row tiles -> 64 rows per wave
#define ROWS    64       // rows per block (= per wave; 1-wave blocks)
#define KS      7        // 7 k-steps of 16 -> K=112 (useful 101)

typedef _Float16 half8  __attribute__((ext_vector_type(8)));
typedef _Float16 half2v __attribute__((ext_vector_type(2)));
typedef __fp16   fp16x2 __attribute__((ext_vector_type(2)));
typedef float    f32x4  __attribute__((ext_vector_type(4)));
typedef float    f32x16 __attribute__((ext_vector_type(16)));
typedef unsigned uint4v __attribute__((ext_vector_type(4)));

// ---------------- workspace layout ----------------
// wsh: [l][ks7][nt4][lane][8] — frag stride 512 halves (1024 B).
// A-frag (32x32x16, operand-swapped W^T): lane -> neuron n = nt*32+(lane&31);
// elem j -> k = ks*16 + (lane>>5)*8 + j.
//   k<100 && n<100   -> Ws[l][k][n]
//   k==100 && n<100  -> bs[l][n]      (bias row vs h col 100 == 1.0)
//   k==100 && n==100 -> 1.0           (bias col self-sustains; W col 100 = e_100)
#define WSH_LAYER_HALVES (KS * NTT * 64 * 8)             // 14336
#define WSH_HALVES       (NLAYERS * WSH_LAYER_HALVES)    // 1,433,600
#define W0_HALVES        (4 * NTT * 64 * 8)              // 8192 (input, K=64 = 4 ks)
#define BPAD_FLOATS      128                             // b_in padded; col 100 = 1.0
#define OFF_BPAD_B       ((WSH_HALVES + W0_HALVES) * 2)
#define OFF_WOUT_B       (OFF_BPAD_B + BPAD_FLOATS * 4)
#define WOUT_FLOATS      128

// ============================================================
// prep v2 (unchanged): one block per (l,ks); coalesced row reads ->
// 8KB LDS f32 tile [16k][128n] -> coalesced half8 frag stores.
// ============================================================
__global__ __launch_bounds__(256)
void actor_prep(const float* __restrict__ Win, const float* __restrict__ bin,
                const float* __restrict__ Ws,  const float* __restrict__ bs,
                const float* __restrict__ Wout,
                _Float16* __restrict__ wsh, _Float16* __restrict__ w0sh,
                float* __restrict__ bpad, float* __restrict__ woutp) {
    __shared__ float tile[16 * 128];
    const int bid = blockIdx.x, tid = threadIdx.x;
    if (bid < NLAYERS * KS) {                       // hidden-layer weights
        const int l = bid / KS, ks = bid % KS;
#pragma unroll
        for (int e = 0; e < 8; ++e) {
            int idx = tid + 256 * e;                // coalesced: tid fastest
            int kk = idx >> 7, nn = idx & 127;
            int k = ks * 16 + kk;
            float v = 0.f;
            if (k < WDIM && nn < WDIM)        v = Ws[(l * WDIM + k) * WDIM + nn];
            else if (k == WDIM && nn < WDIM)  v = bs[l * WDIM + nn];   // bias row
            else if (k == WDIM && nn == WDIM) v = 1.0f;                // bias col alive
            tile[idx] = v;
        }
        __syncthreads();
        const int lane = tid & 63, nt = tid >> 6;
        const int g = lane >> 5, n = nt * 32 + (lane & 31);
        half8 o;
#pragma unroll
        for (int j = 0; j < 8; ++j) o[j] = (_Float16)tile[(g * 8 + j) * 128 + n];
        *(half8*)(wsh + (((l * KS + ks) * NTT + nt) << 9) + lane * 8) = o;
        return;
    }
    int b2 = bid - NLAYERS * KS;
    if (b2 < 4) {                                   // input layer (K=64)
        const int ks = b2;
#pragma unroll
        for (int e = 0; e < 8; ++e) {
            int idx = tid + 256 * e;
            int kk = idx >> 7, nn = idx & 127;
            int k = ks * 16 + kk;                   // < 64
            tile[idx] = (nn < WDIM) ? Win[k * WDIM + nn] : 0.f;
        }
        __syncthreads();
        const int lane = tid & 63, nt = tid >> 6;
        const int g = lane >> 5, n = nt * 32 + (lane & 31);
        half8 o;
#pragma unroll
        for (int j = 0; j < 8; ++j) o[j] = (_Float16)tile[(g * 8 + j) * 128 + n];
        *(half8*)(w0sh + ((ks * NTT + nt) << 9) + lane * 8) = o;
        return;
    }
    // last block: padded b_in (col 100 = 1.0 seed) + padded W_out
    if (tid < BPAD_FLOATS) {
        bpad[tid] = (tid < WDIM) ? bin[tid] : (tid == WDIM ? 1.0f : 0.f);
    } else {
        int t = tid - BPAD_FLOATS;
        if (t < WOUT_FLOATS) woutp[t] = (t < WDIM) ? Wout[t] : 0.f;
    }
}

// split fp32 -> hi/lo fp16 (layer-0 input only: keep input fidelity)
__device__ __forceinline__ void split8(const float* __restrict__ p, half8& hi, half8& lo) {
    f32x4 u0 = *(const f32x4*)p;
    f32x4 u1 = *(const f32x4*)(p + 4);
    float v[8] = {u0[0], u0[1], u0[2], u0[3], u1[0], u1[1], u1[2], u1[3]};
#pragma unroll
    for (int e = 0; e < 8; e += 2) {
        fp16x2 h = __builtin_amdgcn_cvt_pkrtz(v[e], v[e + 1]);
        float r0 = v[e]     - (float)h[0];
        float r1 = v[e + 1] - (float)h[1];
        fp16x2 l = __builtin_amdgcn_cvt_pkrtz(r0, r1);
        hi[e] = (_Float16)h[0]; hi[e + 1] = (_Float16)h[1];
        lo[e] = (_Float16)l[0]; lo[e + 1] = (_Float16)l[1];
    }
}

// RNE f16 cast pair + packed-f16 leaky -> one dword (same ops/precision
// as the original LDS epilogue: scalar RNE cast, then max(p, 0.01p) in f16)
__device__ __forceinline__ unsigned pack2(float a, float b) {
    half2v p; p[0] = (_Float16)a; p[1] = (_Float16)b;
    const half2v slope = {(_Float16)0.01f, (_Float16)0.01f};
    p = __builtin_elementwise_max(p, p * slope);
    return __builtin_bit_cast(unsigned, p);
}

// acc -> bh: leaky+f16 pack + lane-half exchange (v_permlane32_swap).
// C/D layout (m74/m101): col=b31, row=(reg&3)+8*(reg>>2)+4g. B-frag:
// lane b31 holds k=ks*16+g*8+j. Elems j0..3 come from lane b31 regs
// r0=8*(ks&1)+0..3, j4..7 from lane b31+32 same regs -> one permlane
// swap per dword pair routes both halves. Bit-identical to the LDS
// path (verified: absmax constant 0.09375 since r17).
__device__ __forceinline__ void pack_bh(const f32x16 (&acc)[RT][NTT], half8 (&bh)[RT][KS]) {
#pragma unroll
    for (int rt = 0; rt < RT; ++rt)
#pragma unroll
        for (int ks = 0; ks < KS; ++ks) {
            const int r0 = 8 * (ks & 1);
            const f32x16 a = acc[rt][ks >> 1];
            unsigned lo0 = pack2(a[r0 + 0], a[r0 + 1]);
            unsigned lo1 = pack2(a[r0 + 2], a[r0 + 3]);
            unsigned hi0 = pack2(a[r0 + 4], a[r0 + 5]);
            unsigned hi1 = pack2(a[r0 + 6], a[r0 + 7]);
            asm volatile("v_permlane32_swap_b32 %0, %1" : "+v"(lo0), "+v"(hi0));
            asm volatile("v_permlane32_swap_b32 %0, %1" : "+v"(lo1), "+v"(hi1));
            uint4v u = {lo0, lo1, hi0, hi1};
            bh[rt][ks] = __builtin_bit_cast(half8, u);
        }
}

static __device__ const f32x16 kZero16 = {0,0,0,0, 0,0,0,0, 0,0,0,0, 0,0,0,0};

// one hidden layer: 56 MFMAs (8 independent chains) consuming wb;
// wb[ks] is dead after its 8 MFMAs -> refill from wn (next owner layer).
// No anchors, no drains: the refill's wait is a counted vmcnt at its
// use ~1.5-2 layers later.
__device__ __forceinline__ void layer_mfma(f32x16 (&acc)[RT][NTT], const half8 (&bh)[RT][KS],
                                           half8 (&wb)[KS][NTT],
                                           const _Float16* __restrict__ wn, int lane) {
#pragma unroll
    for (int ks = 0; ks < KS; ++ks) {
#pragma unroll
        for (int rt = 0; rt < RT; ++rt)
#pragma unroll
            for (int nt = 0; nt < NTT; ++nt)
                acc[rt][nt] = __builtin_amdgcn_mfma_f32_32x32x16_f16(
                    wb[ks][nt], bh[rt][ks], (ks == 0 ? kZero16 : acc[rt][nt]), 0, 0, 0);
#pragma unroll
        for (int nt = 0; nt < NTT; ++nt)
            wb[ks][nt] = *(const half8*)(wn + (ks * NTT + nt) * 512 + lane * 8);
    }
}

// ============================================================
// Main r22: zero-LDS register handoff (r21) + TRUE double-buffered W.
// Post-mortem r21 (225us, VGPR=212): the keep-alive anchor forced a
// full vmcnt DRAIN of all 28 W refills at every layer end (asm "+v"
// pins completion, not just issue), and 212<296 showed the compiler
// deferred refill issue under pressure — per-layer serial stall; wave
// idle ~75% (MfmaUtil 37 = 1792cy busy vs 4850cy wall per CU-layer).
// Fix: unroll layers by 2 with TWO register W buffers — even layers
// consume wbA / refill wbA=W(l+2), odd consume wbB / refill wbB=W(l+3).
// ~2 layers of slack per load, counted-vmcnt waits at use (T4), no
// drain point anywhere. Unroll-by-2 also puts pack(l) and MFMA(l+1) in
// one straight-line region -> scheduler overlaps the pack VALU tail
// (which must follow the full acc chain) with next-layer MFMA issue.
// Budget: acc 128 + wbA 112 + wbB 112 + bh 56 ~ 430 VGPR -> 1 wave/SIMD
// (launch_bounds(64,1), 512-reg budget, no spill through ~450 [m08]).
// Issue floor/layer ~448cy MFMA + ~700cy pack, partly overlapped.
// W traffic: 4 waves/CU x 28KB same stream (L1-broadcast); wsh 2.87MB
// L2-resident per XCD. VGPR_Count is the design-survival signature:
// expect 380-470; <=260 means the compiler sank wbB again.
// ============================================================
__global__ __launch_bounds__(64, 1)
void actor_main(const float* __restrict__ x,
                const _Float16* __restrict__ wsh,
                const _Float16* __restrict__ w0sh,
                const float* __restrict__ bpad,
                const float* __restrict__ woutp,
                const float* __restrict__ bout,
                float* __restrict__ out) {
    const int lane = threadIdx.x;                // 0..63 (one wave)
    const int g = lane >> 5, b31 = lane & 31;
    const int rowbase = blockIdx.x * ROWS;

    f32x16 acc[RT][NTT];             // 128 VGPR: 8 independent MFMA chains
    half8 wbA[KS][NTT];              // 112 VGPR: W for even layers
    half8 wbB[KS][NTT];              // 112 VGPR: W for odd layers
    half8 bh[RT][KS];                //  56 VGPR: B-frags (next-layer input)

    // ---- input layer (K=64 = 4 k-steps of 16), x hi/lo f16 split ----
    {
        half8 w0[4][NTT];
#pragma unroll
        for (int ks = 0; ks < 4; ++ks)
#pragma unroll
            for (int nt = 0; nt < NTT; ++nt)
                w0[ks][nt] = *(const half8*)(w0sh + (ks * NTT + nt) * 512 + lane * 8);
#pragma unroll
        for (int rt = 0; rt < RT; ++rt)
#pragma unroll
            for (int nt = 0; nt < NTT; ++nt)
#pragma unroll
                for (int qd = 0; qd < 4; ++qd) {
                    f32x4 tq = *(const f32x4*)(bpad + nt * 32 + 8 * qd + 4 * g);
#pragma unroll
                    for (int r = 0; r < 4; ++r) acc[rt][nt][4 * qd + r] = tq[r];
                }
#pragma unroll
        for (int rt = 0; rt < RT; ++rt) {
            const float* xr = x + (rowbase + rt * 32 + b31) * DIN;
#pragma unroll
            for (int ks = 0; ks < 4; ++ks) {
                half8 xhi, xlo;
                split8(xr + ks * 16 + g * 8, xhi, xlo);
#pragma unroll
                for (int nt = 0; nt < NTT; ++nt) {
                    acc[rt][nt] = __builtin_amdgcn_mfma_f32_32x32x16_f16(w0[ks][nt], xhi, acc[rt][nt], 0, 0, 0);
                    acc[rt][nt] = __builtin_amdgcn_mfma_f32_32x32x16_f16(w0[ks][nt], xlo, acc[rt][nt], 0, 0, 0);
                }
            }
        }
    }
    // issue W(0)/W(1) loads first (they overlap the pack below), then
    // build bh (h0) in regs
#pragma unroll
    for (int ks = 0; ks < KS; ++ks)
#pragma unroll
        for (int nt = 0; nt < NTT; ++nt) {
            wbA[ks][nt] = *(const half8*)(wsh + (ks * NTT + nt) * 512 + lane * 8);
            wbB[ks][nt] = *(const half8*)(wsh + WSH_LAYER_HALVES + (ks * NTT + nt) * 512 + lane * 8);
        }
    pack_bh(acc, bh);

    // -------- 100 hidden layers, unrolled by 2: no LDS, no barriers,
    // -------- no drains; W double-buffered in registers --------
#pragma unroll 1
    for (int l = 0; l < NLAYERS; l += 2) {
        const int lA = (l + 2 < NLAYERS) ? l + 2 : NLAYERS - 1;   // next even
        const int lB = (l + 3 < NLAYERS) ? l + 3 : NLAYERS - 1;   // next odd
        // even layer l: consume wbA, refill wbA = W(lA)
        layer_mfma(acc, bh, wbA, wsh + lA * WSH_LAYER_HALVES, lane);
        pack_bh(acc, bh);                 // input of layer l+1 (l<=98 always)
        // odd layer l+1: consume wbB, refill wbB = W(lB)
        layer_mfma(acc, bh, wbB, wsh + lB * WSH_LAYER_HALVES, lane);
        if (l + 1 < NLAYERS - 1)
            pack_bh(acc, bh);             // input of layer l+2
    }
    // acc[rt][nt] = pre-activation of layer 99 (f32) for all 128 neurons

    // ---------------- head: leaky + dot(W_out), wave-local ----------------
    float part[RT];
#pragma unroll
    for (int rt = 0; rt < RT; ++rt) {
        float s = 0.f;
#pragma unroll
        for (int nt = 0; nt < NTT; ++nt)
#pragma unroll
            for (int qd = 0; qd < 4; ++qd) {
                f32x4 w4 = *(const f32x4*)(woutp + nt * 32 + 8 * qd + 4 * g);
#pragma unroll
                for (int r = 0; r < 4; ++r) {
                    float a = acc[rt][nt][4 * qd + r];
                    float v = fmaxf(a, 0.01f * a);
                    s += v * w4[r];
                }
            }
        s += __shfl_xor(s, 32);          // combine the two k-groups (same batch row)
        part[rt] = s;
    }
    if (lane < 32) {
#pragma unroll
        for (int rt = 0; rt < RT; ++rt) {
            float tot = part[rt] + bout[0];
            out[rowbase + rt * 32 + b31] = tanhf(tot) * 4.5f + 5.5f;   // (tanh+1)/2*9+1
        }
    }
}

extern "C" void kernel_launch(void* const* d_in, const int* in_sizes, int n_in,
                              void* d_out, int out_size, void* d_ws, size_t ws_size,
                              hipStream_t stream) {
    const float* x    = (const float*)d_in[0];
    const float* Win  = (const float*)d_in[1];
    const float* bin  = (const float*)d_in[2];
    const float* Ws   = (const float*)d_in[3];
    const float* bs   = (const float*)d_in[4];
    const float* Wout = (const float*)d_in[5];
    const float* bout = (const float*)d_in[6];
    float* out = (float*)d_out;

    char* ws = (char*)d_ws;
    _Float16* wsh  = (_Float16*)ws;
    _Float16* w0sh = wsh + WSH_HALVES;
    float* bpad  = (float*)(ws + OFF_BPAD_B);
    float* woutp = (float*)(ws + OFF_WOUT_B);

    hipLaunchKernelGGL(actor_prep, dim3(NLAYERS * KS + 4 + 1), dim3(256), 0, stream,
                       Win, bin, Ws, bs, Wout, wsh, w0sh, bpad, woutp);

    const int nrows = in_sizes[0] / DIN;   // 65536
    hipLaunchKernelGGL(actor_main, dim3(nrows / ROWS), dim3(64), 0, stream,
                       x, wsh, w0sh, bpad, woutp, bout, out);
}

// Round 6
// 263.695 us; speedup vs baseline: 1.3026x; 1.3026x over previous
//
#include <hip/hip_runtime.h>
#include <cmath>

// ---------------- problem constants ----------------
#define NLAYERS 100      // hidden layers (scan)
#define DIN     64       // input features
#define WDIM    100      // hidden width
#define NTT     4        // 4 n-tiles of 32 (128 neuron cols; bias col = 100)
#define RT      2        // two 32-row tiles -> 64 rows per wave
#define ROWS    64       // rows per WAVE
#define WAVES   2        // waves per block
#define BROWS   (WAVES * ROWS)   // 128 rows per block
#define KS      7        // 7 k-steps of 16 -> K=112 (useful 101)
#define FRAGS   (KS * NTT)       // 28 W frags per layer
#define FPW     (FRAGS / WAVES)  // 14 frags staged per wave

typedef _Float16 half8  __attribute__((ext_vector_type(8)));
typedef _Float16 half2v __attribute__((ext_vector_type(2)));
typedef __fp16   fp16x2 __attribute__((ext_vector_type(2)));
typedef float    f32x4  __attribute__((ext_vector_type(4)));
typedef float    f32x16 __attribute__((ext_vector_type(16)));
typedef unsigned uint4v __attribute__((ext_vector_type(4)));

// ---------------- workspace layout ----------------
// wsh: [l][ks7][nt4][lane][8] — frag stride 512 halves (1024 B).
// A-frag (32x32x16, operand-swapped W^T): lane -> neuron n = nt*32+(lane&31);
// elem j -> k = ks*16 + (lane>>5)*8 + j.
//   k<100 && n<100   -> Ws[l][k][n]
//   k==100 && n<100  -> bs[l][n]      (bias row vs h col 100 == 1.0)
//   k==100 && n==100 -> 1.0           (bias col self-sustains)
// This frag layout is EXACTLY the global_load_lds pattern: per-lane 16B
// contiguous source, wave-uniform LDS destination base.
#define WSH_LAYER_HALVES (KS * NTT * 64 * 8)             // 14336 (28672 B)
#define WSH_HALVES       (NLAYERS * WSH_LAYER_HALVES)    // 1,433,600
#define W0_HALVES        (4 * NTT * 64 * 8)              // 8192 (input, K=64 = 4 ks)
#define BPAD_FLOATS      128                             // b_in padded; col 100 = 1.0
#define OFF_BPAD_B       ((WSH_HALVES + W0_HALVES) * 2)
#define OFF_WOUT_B       (OFF_BPAD_B + BPAD_FLOATS * 4)
#define WOUT_FLOATS      128

// ============================================================
// prep v2 (unchanged): one block per (l,ks); coalesced row reads ->
// 8KB LDS f32 tile [16k][128n] -> coalesced half8 frag stores.
// ============================================================
__global__ __launch_bounds__(256)
void actor_prep(const float* __restrict__ Win, const float* __restrict__ bin,
                const float* __restrict__ Ws,  const float* __restrict__ bs,
                const float* __restrict__ Wout,
                _Float16* __restrict__ wsh, _Float16* __restrict__ w0sh,
                float* __restrict__ bpad, float* __restrict__ woutp) {
    __shared__ float tile[16 * 128];
    const int bid = blockIdx.x, tid = threadIdx.x;
    if (bid < NLAYERS * KS) {                       // hidden-layer weights
        const int l = bid / KS, ks = bid % KS;
#pragma unroll
        for (int e = 0; e < 8; ++e) {
            int idx = tid + 256 * e;                // coalesced: tid fastest
            int kk = idx >> 7, nn = idx & 127;
            int k = ks * 16 + kk;
            float v = 0.f;
            if (k < WDIM && nn < WDIM)        v = Ws[(l * WDIM + k) * WDIM + nn];
            else if (k == WDIM && nn < WDIM)  v = bs[l * WDIM + nn];   // bias row
            else if (k == WDIM && nn == WDIM) v = 1.0f;                // bias col alive
            tile[idx] = v;
        }
        __syncthreads();
        const int lane = tid & 63, nt = tid >> 6;
        const int g = lane >> 5, n = nt * 32 + (lane & 31);
        half8 o;
#pragma unroll
        for (int j = 0; j < 8; ++j) o[j] = (_Float16)tile[(g * 8 + j) * 128 + n];
        *(half8*)(wsh + (((l * KS + ks) * NTT + nt) << 9) + lane * 8) = o;
        return;
    }
    int b2 = bid - NLAYERS * KS;
    if (b2 < 4) {                                   // input layer (K=64)
        const int ks = b2;
#pragma unroll
        for (int e = 0; e < 8; ++e) {
            int idx = tid + 256 * e;
            int kk = idx >> 7, nn = idx & 127;
            int k = ks * 16 + kk;                   // < 64
            tile[idx] = (nn < WDIM) ? Win[k * WDIM + nn] : 0.f;
        }
        __syncthreads();
        const int lane = tid & 63, nt = tid >> 6;
        const int g = lane >> 5, n = nt * 32 + (lane & 31);
        half8 o;
#pragma unroll
        for (int j = 0; j < 8; ++j) o[j] = (_Float16)tile[(g * 8 + j) * 128 + n];
        *(half8*)(w0sh + ((ks * NTT + nt) << 9) + lane * 8) = o;
        return;
    }
    // last block: padded b_in (col 100 = 1.0 seed) + padded W_out
    if (tid < BPAD_FLOATS) {
        bpad[tid] = (tid < WDIM) ? bin[tid] : (tid == WDIM ? 1.0f : 0.f);
    } else {
        int t = tid - BPAD_FLOATS;
        if (t < WOUT_FLOATS) woutp[t] = (t < WDIM) ? Wout[t] : 0.f;
    }
}

// async global->LDS, 16 B per lane, zero VGPR cost.
// g: per-lane source (base + lane*16B); l: WAVE-UNIFORM LDS frag base
// (HW adds lane*16). [m97: emits global_load_lds_dwordx4]
__device__ __forceinline__ void stage16(const _Float16* __restrict__ g,
                                        _Float16* l) {
    __builtin_amdgcn_global_load_lds(
        (const __attribute__((address_space(1))) unsigned*)g,
        (__attribute__((address_space(3))) unsigned*)l, 16, 0, 0);
}

// split fp32 -> hi/lo fp16 (layer-0 input only: keep input fidelity)
__device__ __forceinline__ void split8(const float* __restrict__ p, half8& hi, half8& lo) {
    f32x4 u0 = *(const f32x4*)p;
    f32x4 u1 = *(const f32x4*)(p + 4);
    float v[8] = {u0[0], u0[1], u0[2], u0[3], u1[0], u1[1], u1[2], u1[3]};
#pragma unroll
    for (int e = 0; e < 8; e += 2) {
        fp16x2 h = __builtin_amdgcn_cvt_pkrtz(v[e], v[e + 1]);
        float r0 = v[e]     - (float)h[0];
        float r1 = v[e + 1] - (float)h[1];
        fp16x2 l = __builtin_amdgcn_cvt_pkrtz(r0, r1);
        hi[e] = (_Float16)h[0]; hi[e + 1] = (_Float16)h[1];
        lo[e] = (_Float16)l[0]; lo[e + 1] = (_Float16)l[1];
    }
}

// RNE f16 cast pair + packed-f16 leaky -> one dword (same ops/precision
// as the original LDS epilogue: scalar RNE cast, then max(p, 0.01p) in f16)
__device__ __forceinline__ unsigned pack2(float a, float b) {
    half2v p; p[0] = (_Float16)a; p[1] = (_Float16)b;
    const half2v slope = {(_Float16)0.01f, (_Float16)0.01f};
    p = __builtin_elementwise_max(p, p * slope);
    return __builtin_bit_cast(unsigned, p);
}

// acc -> bh: leaky+f16 pack + lane-half exchange (v_permlane32_swap).
// C/D layout (m74/m101): col=b31, row=(reg&3)+8*(reg>>2)+4g. B-frag:
// lane b31 holds k=ks*16+g*8+j; j0..3 from lane b31 regs r0=8*(ks&1)+0..3,
// j4..7 from lane b31+32 same regs -> one permlane swap per dword pair.
// Bit-identical to the LDS h path (absmax constant 0.09375 since r17).
__device__ __forceinline__ void pack_bh(const f32x16 (&acc)[RT][NTT], half8 (&bh)[RT][KS]) {
#pragma unroll
    for (int rt = 0; rt < RT; ++rt)
#pragma unroll
        for (int ks = 0; ks < KS; ++ks) {
            const int r0 = 8 * (ks & 1);
            const f32x16 a = acc[rt][ks >> 1];
            unsigned lo0 = pack2(a[r0 + 0], a[r0 + 1]);
            unsigned lo1 = pack2(a[r0 + 2], a[r0 + 3]);
            unsigned hi0 = pack2(a[r0 + 4], a[r0 + 5]);
            unsigned hi1 = pack2(a[r0 + 6], a[r0 + 7]);
            asm volatile("v_permlane32_swap_b32 %0, %1" : "+v"(lo0), "+v"(hi0));
            asm volatile("v_permlane32_swap_b32 %0, %1" : "+v"(lo1), "+v"(hi1));
            uint4v u = {lo0, lo1, hi0, hi1};
            bh[rt][ks] = __builtin_bit_cast(half8, u);
        }
}

static __device__ const f32x16 kZero16 = {0,0,0,0, 0,0,0,0, 0,0,0,0, 0,0,0,0};

// ============================================================
// Main r23: register h-handoff (r21) + W double-buffered in LDS via
// global_load_lds (zero-VGPR staging).
// Post-mortem r22 (299us): VGPR_Count=256 = the ARCH-VGPR ceiling;
// WRITE_SIZE 7936KB = scratch spill. acc128+W112(+112)+bh56 can never
// fit — every r19-r22 failure is this one deadlock (compiler either
// sinks W loads or spills). Fix: W lookahead costs ZERO VGPRs via
// global_load_lds into a 2x28KB LDS double-buffer (LDS was free since
// r21). Blocks = 2 waves x 64 rows (grid 512, 2 blk/CU, 114KB LDS/CU);
// each wave stages 14/28 frags; ONE __syncthreads per layer (its
// vmcnt(0) drains staging issued a full layer earlier -> ~free).
// W consumed through a 3-slot x 4-frag register window (48 VGPR),
// distance-2 ds_read prefetch (128cy MFMA cover >= ~120cy ds latency).
// Budget: acc128 + bh56 + win48 + temps ~ 245 <= 256 (launch_bounds
// (128,2) caps at 256 -> no spill by construction).
// Per-CU-layer: LDS pipe ~1600cy (4x28 ds_read_b128 + 56 staged
// writes) = designed bottleneck; per-SIMD issue 448 MFMA + ~620 pack;
// VMEM 56KB from L2 (wsh 2.87MB L2-resident). ~1600cy x 100 ~ 67us.
// h handoff: in-register permlane (zero LDS h traffic, no h barrier);
// W bytes identical through LDS -> absmax 0.09375 unchanged.
// ============================================================
__global__ __launch_bounds__(128, 2)
void actor_main(const float* __restrict__ x,
                const _Float16* __restrict__ wsh,
                const _Float16* __restrict__ w0sh,
                const float* __restrict__ bpad,
                const float* __restrict__ woutp,
                const float* __restrict__ bout,
                float* __restrict__ out) {
    __shared__ __align__(16) _Float16 wlds[2 * WSH_LAYER_HALVES];  // 57344 B
    const int tid  = threadIdx.x;
    const int lane = tid & 63;
    const int wid  = tid >> 6;                   // 0..1
    const int g = lane >> 5, b31 = lane & 31;
    const int rowbase = blockIdx.x * BROWS + wid * ROWS;   // my wave's 64 rows

    f32x16 acc[RT][NTT];             // 128 VGPR: 8 independent MFMA chains
    half8 bh[RT][KS];                //  56 VGPR: B-frags (next-layer input)
    half8 wreg[3][NTT];              //  48 VGPR: W window, distance-2 prefetch

    // ---- stage W(0) -> buf0 (async; overlaps entire input layer) ----
#pragma unroll
    for (int f = 0; f < FPW; ++f) {
        const int fr = wid * FPW + f;
        stage16(wsh + fr * 512 + lane * 8, wlds + fr * 512);
    }

    // ---- input layer (K=64 = 4 k-steps of 16), x hi/lo f16 split ----
    {
        half8 w0[4][NTT];
#pragma unroll
        for (int ks = 0; ks < 4; ++ks)
#pragma unroll
            for (int nt = 0; nt < NTT; ++nt)
                w0[ks][nt] = *(const half8*)(w0sh + (ks * NTT + nt) * 512 + lane * 8);
#pragma unroll
        for (int rt = 0; rt < RT; ++rt)
#pragma unroll
            for (int nt = 0; nt < NTT; ++nt)
#pragma unroll
                for (int qd = 0; qd < 4; ++qd) {
                    f32x4 tq = *(const f32x4*)(bpad + nt * 32 + 8 * qd + 4 * g);
#pragma unroll
                    for (int r = 0; r < 4; ++r) acc[rt][nt][4 * qd + r] = tq[r];
                }
#pragma unroll
        for (int rt = 0; rt < RT; ++rt) {
            const float* xr = x + (rowbase + rt * 32 + b31) * DIN;
#pragma unroll
            for (int ks = 0; ks < 4; ++ks) {
                half8 xhi, xlo;
                split8(xr + ks * 16 + g * 8, xhi, xlo);
#pragma unroll
                for (int nt = 0; nt < NTT; ++nt) {
                    acc[rt][nt] = __builtin_amdgcn_mfma_f32_32x32x16_f16(w0[ks][nt], xhi, acc[rt][nt], 0, 0, 0);
                    acc[rt][nt] = __builtin_amdgcn_mfma_f32_32x32x16_f16(w0[ks][nt], xlo, acc[rt][nt], 0, 0, 0);
                }
            }
        }
    }
    pack_bh(acc, bh);                // h0 in regs
    __syncthreads();                 // drains W(0) staging (vmcnt(0) + barrier)

    // -------- 100 hidden layers: 1 barrier/layer, zero-VGPR W pipeline ------
#pragma unroll 1
    for (int l = 0; l < NLAYERS; ++l) {
        const _Float16* rb = wlds + (l & 1) * WSH_LAYER_HALVES;        // W(l)
        _Float16* sb = wlds + ((l + 1) & 1) * WSH_LAYER_HALVES;        // W(l+1) dest
        const int ln = (l + 1 < NLAYERS) ? l + 1 : NLAYERS - 1;
        const _Float16* wn = wsh + ln * WSH_LAYER_HALVES;

        // issue next-layer staging FIRST (max slack; completes under this
        // layer's compute; drained by the end-of-layer __syncthreads)
#pragma unroll
        for (int f = 0; f < FPW; ++f) {
            const int fr = wid * FPW + f;
            stage16(wn + fr * 512 + lane * 8, sb + fr * 512);
        }
        // W window preload: ks0, ks1
#pragma unroll
        for (int kp = 0; kp < 2; ++kp)
#pragma unroll
            for (int nt = 0; nt < NTT; ++nt)
                wreg[kp][nt] = *(const half8*)(rb + (kp * NTT + nt) * 512 + lane * 8);
        // 56 MFMAs (8 chains) + distance-2 ds_read prefetch
#pragma unroll
        for (int ks = 0; ks < KS; ++ks) {
            const int s = ks % 3;
#pragma unroll
            for (int rt = 0; rt < RT; ++rt)
#pragma unroll
                for (int nt = 0; nt < NTT; ++nt)
                    acc[rt][nt] = __builtin_amdgcn_mfma_f32_32x32x16_f16(
                        wreg[s][nt], bh[rt][ks], (ks == 0 ? kZero16 : acc[rt][nt]), 0, 0, 0);
            if (ks + 2 < KS) {
                const int s2 = (ks + 2) % 3;
#pragma unroll
                for (int nt = 0; nt < NTT; ++nt)
                    wreg[s2][nt] = *(const half8*)(rb + ((ks + 2) * NTT + nt) * 512 + lane * 8);
            }
        }
        if (l < NLAYERS - 1)
            pack_bh(acc, bh);        // next layer's input (regs only)
        __syncthreads();             // staging drained + visible to both waves
    }
    // acc[rt][nt] = pre-activation of layer 99 (f32) for all 128 neurons

    // ---------------- head: leaky + dot(W_out), wave-local ----------------
    float part[RT];
#pragma unroll
    for (int rt = 0; rt < RT; ++rt) {
        float s = 0.f;
#pragma unroll
        for (int nt = 0; nt < NTT; ++nt)
#pragma unroll
            for (int qd = 0; qd < 4; ++qd) {
                f32x4 w4 = *(const f32x4*)(woutp + nt * 32 + 8 * qd + 4 * g);
#pragma unroll
                for (int r = 0; r < 4; ++r) {
                    float a = acc[rt][nt][4 * qd + r];
                    float v = fmaxf(a, 0.01f * a);
                    s += v * w4[r];
                }
            }
        s += __shfl_xor(s, 32);      // combine the two k-groups (same batch row)
        part[rt] = s;
    }
    if (lane < 32) {
#pragma unroll
        for (int rt = 0; rt < RT; ++rt) {
            float tot = part[rt] + bout[0];
            out[rowbase + rt * 32 + b31] = tanhf(tot) * 4.5f + 5.5f;   // (tanh+1)/2*9+1
        }
    }
}

extern "C" void kernel_launch(void* const* d_in, const int* in_sizes, int n_in,
                              void* d_out, int out_size, void* d_ws, size_t ws_size,
                              hipStream_t stream) {
    const float* x    = (const float*)d_in[0];
    const float* Win  = (const float*)d_in[1];
    const float* bin  = (const float*)d_in[2];
    const float* Ws   = (const float*)d_in[3];
    const float* bs   = (const float*)d_in[4];
    const float* Wout = (const float*)d_in[5];
    const float* bout = (const float*)d_in[6];
    float* out = (float*)d_out;

    char* ws = (char*)d_ws;
    _Float16* wsh  = (_Float16*)ws;
    _Float16* w0sh = wsh + WSH_HALVES;
    float* bpad  = (float*)(ws + OFF_BPAD_B);
    float* woutp = (float*)(ws + OFF_WOUT_B);

    hipLaunchKernelGGL(actor_prep, dim3(NLAYERS * KS + 4 + 1), dim3(256), 0, stream,
                       Win, bin, Ws, bs, Wout, wsh, w0sh, bpad, woutp);

    const int nrows = in_sizes[0] / DIN;   // 65536
    hipLaunchKernelGGL(actor_main, dim3(nrows / BROWS), dim3(WAVES * 64), 0, stream,
                       x, wsh, w0sh, bpad, woutp, bout, out);
}

// Round 7
// 246.985 us; speedup vs baseline: 1.3908x; 1.0677x over previous
//
#include <hip/hip_runtime.h>
#include <cmath>

// ---------------- problem constants ----------------
#define NLAYERS 100      // hidden layers (scan)
#define DIN     64       // input features
#define WDIM    100      // hidden width
#define NTT     4        // 4 n-tiles of 32 (128 neuron cols; bias col = 100)
#define ROWS    32       // rows per WAVE (RT=1)
#define WAVES   4        // waves per block
#define BROWS   (WAVES * ROWS)   // 128 rows per block
#define KS      7        // 7 k-steps of 16 -> K=112 (useful 101)
#define FRAGS   (KS * NTT)       // 28 W frags per layer
#define FPW     (FRAGS / WAVES)  // 7 frags staged per wave

typedef _Float16 half8  __attribute__((ext_vector_type(8)));
typedef _Float16 half2v __attribute__((ext_vector_type(2)));
typedef __fp16   fp16x2 __attribute__((ext_vector_type(2)));
typedef float    f32x4  __attribute__((ext_vector_type(4)));
typedef float    f32x16 __attribute__((ext_vector_type(16)));
typedef unsigned uint4v __attribute__((ext_vector_type(4)));

// ---------------- workspace layout ----------------
// wsh: [l][ks7][nt4][lane][8] — frag stride 512 halves (1024 B).
// A-frag (32x32x16, operand-swapped W^T): lane -> neuron n = nt*32+(lane&31);
// elem j -> k = ks*16 + (lane>>5)*8 + j.
//   k<100 && n<100   -> Ws[l][k][n]
//   k==100 && n<100  -> bs[l][n]      (bias row vs h col 100 == 1.0)
//   k==100 && n==100 -> 1.0           (bias col self-sustains)
// Frag layout == the global_load_lds pattern: per-lane 16B contiguous
// source, wave-uniform LDS destination base.
#define WSH_LAYER_HALVES (KS * NTT * 64 * 8)             // 14336 (28672 B)
#define WSH_HALVES       (NLAYERS * WSH_LAYER_HALVES)    // 1,433,600
#define W0_HALVES        (4 * NTT * 64 * 8)              // 8192 (input, K=64 = 4 ks)
#define BPAD_FLOATS      128                             // b_in padded; col 100 = 1.0
#define OFF_BPAD_B       ((WSH_HALVES + W0_HALVES) * 2)
#define OFF_WOUT_B       (OFF_BPAD_B + BPAD_FLOATS * 4)
#define WOUT_FLOATS      128

// ============================================================
// prep v2 (unchanged): one block per (l,ks); coalesced row reads ->
// 8KB LDS f32 tile [16k][128n] -> coalesced half8 frag stores.
// ============================================================
__global__ __launch_bounds__(256)
void actor_prep(const float* __restrict__ Win, const float* __restrict__ bin,
                const float* __restrict__ Ws,  const float* __restrict__ bs,
                const float* __restrict__ Wout,
                _Float16* __restrict__ wsh, _Float16* __restrict__ w0sh,
                float* __restrict__ bpad, float* __restrict__ woutp) {
    __shared__ float tile[16 * 128];
    const int bid = blockIdx.x, tid = threadIdx.x;
    if (bid < NLAYERS * KS) {                       // hidden-layer weights
        const int l = bid / KS, ks = bid % KS;
#pragma unroll
        for (int e = 0; e < 8; ++e) {
            int idx = tid + 256 * e;                // coalesced: tid fastest
            int kk = idx >> 7, nn = idx & 127;
            int k = ks * 16 + kk;
            float v = 0.f;
            if (k < WDIM && nn < WDIM)        v = Ws[(l * WDIM + k) * WDIM + nn];
            else if (k == WDIM && nn < WDIM)  v = bs[l * WDIM + nn];   // bias row
            else if (k == WDIM && nn == WDIM) v = 1.0f;                // bias col alive
            tile[idx] = v;
        }
        __syncthreads();
        const int lane = tid & 63, nt = tid >> 6;
        const int g = lane >> 5, n = nt * 32 + (lane & 31);
        half8 o;
#pragma unroll
        for (int j = 0; j < 8; ++j) o[j] = (_Float16)tile[(g * 8 + j) * 128 + n];
        *(half8*)(wsh + (((l * KS + ks) * NTT + nt) << 9) + lane * 8) = o;
        return;
    }
    int b2 = bid - NLAYERS * KS;
    if (b2 < 4) {                                   // input layer (K=64)
        const int ks = b2;
#pragma unroll
        for (int e = 0; e < 8; ++e) {
            int idx = tid + 256 * e;
            int kk = idx >> 7, nn = idx & 127;
            int k = ks * 16 + kk;                   // < 64
            tile[idx] = (nn < WDIM) ? Win[k * WDIM + nn] : 0.f;
        }
        __syncthreads();
        const int lane = tid & 63, nt = tid >> 6;
        const int g = lane >> 5, n = nt * 32 + (lane & 31);
        half8 o;
#pragma unroll
        for (int j = 0; j < 8; ++j) o[j] = (_Float16)tile[(g * 8 + j) * 128 + n];
        *(half8*)(w0sh + ((ks * NTT + nt) << 9) + lane * 8) = o;
        return;
    }
    // last block: padded b_in (col 100 = 1.0 seed) + padded W_out
    if (tid < BPAD_FLOATS) {
        bpad[tid] = (tid < WDIM) ? bin[tid] : (tid == WDIM ? 1.0f : 0.f);
    } else {
        int t = tid - BPAD_FLOATS;
        if (t < WOUT_FLOATS) woutp[t] = (t < WDIM) ? Wout[t] : 0.f;
    }
}

// async global->LDS, 16 B per lane, zero VGPR cost.
// g: per-lane source (base + lane*16B); l: WAVE-UNIFORM LDS frag base
// (HW adds lane*16). [m97: emits global_load_lds_dwordx4]
__device__ __forceinline__ void stage16(const _Float16* __restrict__ g,
                                        _Float16* l) {
    __builtin_amdgcn_global_load_lds(
        (const __attribute__((address_space(1))) unsigned*)g,
        (__attribute__((address_space(3))) unsigned*)l, 16, 0, 0);
}

// split fp32 -> hi/lo fp16 (layer-0 input only: keep input fidelity)
__device__ __forceinline__ void split8(const float* __restrict__ p, half8& hi, half8& lo) {
    f32x4 u0 = *(const f32x4*)p;
    f32x4 u1 = *(const f32x4*)(p + 4);
    float v[8] = {u0[0], u0[1], u0[2], u0[3], u1[0], u1[1], u1[2], u1[3]};
#pragma unroll
    for (int e = 0; e < 8; e += 2) {
        fp16x2 h = __builtin_amdgcn_cvt_pkrtz(v[e], v[e + 1]);
        float r0 = v[e]     - (float)h[0];
        float r1 = v[e + 1] - (float)h[1];
        fp16x2 l = __builtin_amdgcn_cvt_pkrtz(r0, r1);
        hi[e] = (_Float16)h[0]; hi[e + 1] = (_Float16)h[1];
        lo[e] = (_Float16)l[0]; lo[e + 1] = (_Float16)l[1];
    }
}

// RNE f16 cast pair + packed-f16 leaky -> one dword (same ops/precision
// as the original LDS epilogue: scalar RNE cast, then max(p, 0.01p) in f16)
__device__ __forceinline__ unsigned pack2(float a, float b) {
    half2v p; p[0] = (_Float16)a; p[1] = (_Float16)b;
    const half2v slope = {(_Float16)0.01f, (_Float16)0.01f};
    p = __builtin_elementwise_max(p, p * slope);
    return __builtin_bit_cast(unsigned, p);
}

// acc -> bh: leaky+f16 pack + lane-half exchange (v_permlane32_swap).
// C/D layout (m74/m101): col=b31, row=(reg&3)+8*(reg>>2)+4g. B-frag:
// lane b31 holds k=ks*16+g*8+j; j0..3 from lane b31 regs r0=8*(ks&1)+0..3,
// j4..7 from lane b31+32 same regs -> one permlane swap per dword pair.
// Bit-identical to the LDS h path (absmax constant 0.09375 since r17).
__device__ __forceinline__ void pack_bh(const f32x16 (&acc)[NTT], half8 (&bh)[KS]) {
#pragma unroll
    for (int ks = 0; ks < KS; ++ks) {
        const int r0 = 8 * (ks & 1);
        const f32x16 a = acc[ks >> 1];
        unsigned lo0 = pack2(a[r0 + 0], a[r0 + 1]);
        unsigned lo1 = pack2(a[r0 + 2], a[r0 + 3]);
        unsigned hi0 = pack2(a[r0 + 4], a[r0 + 5]);
        unsigned hi1 = pack2(a[r0 + 6], a[r0 + 7]);
        asm volatile("v_permlane32_swap_b32 %0, %1" : "+v"(lo0), "+v"(hi0));
        asm volatile("v_permlane32_swap_b32 %0, %1" : "+v"(lo1), "+v"(hi1));
        uint4v u = {lo0, lo1, hi0, hi1};
        bh[ks] = __builtin_bit_cast(half8, u);
    }
}

static __device__ const f32x16 kZero16 = {0,0,0,0, 0,0,0,0, 0,0,0,0, 0,0,0,0};

// ============================================================
// Main r24: r23 pipeline, but 32-ROW WAVES -> 2 waves/SIMD.
// Post-mortem r23 (230us): 64-row waves cap the machine at 1024 waves
// = 4/CU = 1 wave/SIMD; wall 5520cy/layer vs ~1200cy of issue work
// (~78% single-wave latency exposure: ds latency, MFMA dep tails, pack
// serialization, barrier). [Also: MfmaUtil on this chip reads ~4.5x
// true — gfx94x fallback formula; r17/r23 both consistent.]
// Fix: RT=1 (32 rows/wave), 4-wave blocks (256 thr, 128 rows), grid
// 512, 2 blocks/CU -> 8 waves/CU = 2/SIMD. RT=1 frees VGPRs: full
// layer W preloaded to regs in one 28-read burst (wb 112) -- no
// rotating window; compiler's counted-lgkm + the co-resident wave
// cover the burst. Budget: acc 64 + wb 112 + bh 28 + temps ~230 <=
// 256 -> 2 waves/SIMD legal (m69), no spill.
// Pipeline per layer (unchanged mechanics): stage W(l+1) via
// global_load_lds into the other 28KB buffer (zero VGPR, ~full layer
// of slack before the barrier drain), ds_read W(l) -> regs, 28 MFMAs
// (4 indep chains), pack_bh in regs (permlane), 1 __syncthreads.
// Designed bottleneck now the LDS pipe: 224 ds_read_b128 + 56 staged
// writes ~ 3300cy/CU-layer -> ~140us. If confirmed, next lever is
// feeding part of W from L1 (global) to use both pipes.
// h handoff in regs; W bytes identical -> absmax 0.09375 unchanged.
// ============================================================
__global__ __launch_bounds__(256, 2)
void actor_main(const float* __restrict__ x,
                const _Float16* __restrict__ wsh,
                const _Float16* __restrict__ w0sh,
                const float* __restrict__ bpad,
                const float* __restrict__ woutp,
                const float* __restrict__ bout,
                float* __restrict__ out) {
    __shared__ __align__(16) _Float16 wlds[2 * WSH_LAYER_HALVES];  // 57344 B
    const int tid  = threadIdx.x;
    const int lane = tid & 63;
    const int wid  = tid >> 6;                   // 0..3
    const int g = lane >> 5, b31 = lane & 31;
    const int rowbase = blockIdx.x * BROWS + wid * ROWS;   // my wave's 32 rows

    f32x16 acc[NTT];                 //  64 VGPR: 4 independent MFMA chains
    half8 bh[KS];                    //  28 VGPR: B-frags (next-layer input)
    half8 wb[KS][NTT];               // 112 VGPR: full-layer W from LDS

    // ---- stage W(0) -> buf0 (async; overlaps entire input layer) ----
#pragma unroll
    for (int f = 0; f < FPW; ++f) {
        const int fr = wid * FPW + f;
        stage16(wsh + fr * 512 + lane * 8, wlds + fr * 512);
    }

    // ---- input layer (K=64 = 4 k-steps of 16), x hi/lo f16 split ----
    {
        half8 w0[4][NTT];
#pragma unroll
        for (int ks = 0; ks < 4; ++ks)
#pragma unroll
            for (int nt = 0; nt < NTT; ++nt)
                w0[ks][nt] = *(const half8*)(w0sh + (ks * NTT + nt) * 512 + lane * 8);
#pragma unroll
        for (int nt = 0; nt < NTT; ++nt)
#pragma unroll
            for (int qd = 0; qd < 4; ++qd) {
                f32x4 tq = *(const f32x4*)(bpad + nt * 32 + 8 * qd + 4 * g);
#pragma unroll
                for (int r = 0; r < 4; ++r) acc[nt][4 * qd + r] = tq[r];
            }
        const float* xr = x + (rowbase + b31) * DIN;
#pragma unroll
        for (int ks = 0; ks < 4; ++ks) {
            half8 xhi, xlo;
            split8(xr + ks * 16 + g * 8, xhi, xlo);
#pragma unroll
            for (int nt = 0; nt < NTT; ++nt) {
                acc[nt] = __builtin_amdgcn_mfma_f32_32x32x16_f16(w0[ks][nt], xhi, acc[nt], 0, 0, 0);
                acc[nt] = __builtin_amdgcn_mfma_f32_32x32x16_f16(w0[ks][nt], xlo, acc[nt], 0, 0, 0);
            }
        }
    }
    pack_bh(acc, bh);                // h0 in regs
    __syncthreads();                 // drains W(0) staging (vmcnt(0) + barrier)

    // -------- 100 hidden layers: 1 barrier/layer, zero-VGPR W pipeline ------
#pragma unroll 1
    for (int l = 0; l < NLAYERS; ++l) {
        const _Float16* rb = wlds + (l & 1) * WSH_LAYER_HALVES;        // W(l)
        _Float16* sb = wlds + ((l + 1) & 1) * WSH_LAYER_HALVES;        // W(l+1) dest
        const int ln = (l + 1 < NLAYERS) ? l + 1 : NLAYERS - 1;
        const _Float16* wn = wsh + ln * WSH_LAYER_HALVES;

        // issue next-layer staging FIRST (max slack before the barrier drain)
#pragma unroll
        for (int f = 0; f < FPW; ++f) {
            const int fr = wid * FPW + f;
            stage16(wn + fr * 512 + lane * 8, sb + fr * 512);
        }
        // full-layer W -> regs: one 28-read burst (counted lgkm; the
        // co-resident wave on this SIMD covers the burst latency)
#pragma unroll
        for (int ks = 0; ks < KS; ++ks)
#pragma unroll
            for (int nt = 0; nt < NTT; ++nt)
                wb[ks][nt] = *(const half8*)(rb + (ks * NTT + nt) * 512 + lane * 8);
        // 28 MFMAs, 4 independent chains
#pragma unroll
        for (int ks = 0; ks < KS; ++ks)
#pragma unroll
            for (int nt = 0; nt < NTT; ++nt)
                acc[nt] = __builtin_amdgcn_mfma_f32_32x32x16_f16(
                    wb[ks][nt], bh[ks], (ks == 0 ? kZero16 : acc[nt]), 0, 0, 0);
        if (l < NLAYERS - 1)
            pack_bh(acc, bh);        // next layer's input (regs only)
        __syncthreads();             // staging drained + buffers flip
    }
    // acc[nt] = pre-activation of layer 99 (f32) for all 128 neurons

    // ---------------- head: leaky + dot(W_out), wave-local ----------------
    float s = 0.f;
#pragma unroll
    for (int nt = 0; nt < NTT; ++nt)
#pragma unroll
        for (int qd = 0; qd < 4; ++qd) {
            f32x4 w4 = *(const f32x4*)(woutp + nt * 32 + 8 * qd + 4 * g);
#pragma unroll
            for (int r = 0; r < 4; ++r) {
                float a = acc[nt][4 * qd + r];
                float v = fmaxf(a, 0.01f * a);
                s += v * w4[r];
            }
        }
    s += __shfl_xor(s, 32);          // combine the two k-groups (same batch row)
    if (lane < 32) {
        float tot = s + bout[0];
        out[rowbase + b31] = tanhf(tot) * 4.5f + 5.5f;   // (tanh+1)/2*9 + 1
    }
}

extern "C" void kernel_launch(void* const* d_in, const int* in_sizes, int n_in,
                              void* d_out, int out_size, void* d_ws, size_t ws_size,
                              hipStream_t stream) {
    const float* x    = (const float*)d_in[0];
    const float* Win  = (const float*)d_in[1];
    const float* bin  = (const float*)d_in[2];
    const float* Ws   = (const float*)d_in[3];
    const float* bs   = (const float*)d_in[4];
    const float* Wout = (const float*)d_in[5];
    const float* bout = (const float*)d_in[6];
    float* out = (float*)d_out;

    char* ws = (char*)d_ws;
    _Float16* wsh  = (_Float16*)ws;
    _Float16* w0sh = wsh + WSH_HALVES;
    float* bpad  = (float*)(ws + OFF_BPAD_B);
    float* woutp = (float*)(ws + OFF_WOUT_B);

    hipLaunchKernelGGL(actor_prep, dim3(NLAYERS * KS + 4 + 1), dim3(256), 0, stream,
                       Win, bin, Ws, bs, Wout, wsh, w0sh, bpad, woutp);

    const int nrows = in_sizes[0] / DIN;   // 65536
    hipLaunchKernelGGL(actor_main, dim3(nrows / BROWS), dim3(WAVES * 64), 0, stream,
                       x, wsh, w0sh, bpad, woutp, bout, out);
}